// Round 1
// baseline (4104.746 us; speedup 1.0000x reference)
//
#include <hip/hip_runtime.h>
#include <math.h>

#define Bn  16
#define Hd  1024
#define COn 512
#define NVn 2048
#define NQn 2048

#define BM 64
#define BN 64
#define BK 16
#define LDT 68   // padded LDS row (68%4==0 keeps float4 alignment, breaks bank conflicts)

// Generic stride-parameterized fp32 GEMM: C[m,n] = sum_k A[m*sAm+k*sAk]*B[k*sBk+n*sBn] (+bias)
// Requires M,N multiples of 64, K multiple of 16, all strides multiples of 4.
// Exactly one of (sAk==1, sAm==1) and one of (sBn==1, sBk==1) must hold.
__global__ __launch_bounds__(256) void gemm_kernel(
    const float* __restrict__ A, const float* __restrict__ Bm, float* __restrict__ C,
    const float* __restrict__ bias,
    int M, int N, int K,
    int sAm, int sAk, long batchA,
    int sBk, int sBn, long batchB,
    long batchC)
{
    __shared__ float As[BK][LDT];
    __shared__ float Bs[BK][LDT];
    const int tid = threadIdx.x;
    const int b   = blockIdx.z;
    const int m0  = blockIdx.y * BM;
    const int n0  = blockIdx.x * BN;
    const float* Ab = A  + (long)b * batchA;
    const float* Bb = Bm + (long)b * batchB;
    const int tm = tid >> 4, tn = tid & 15;
    float acc[4][4] = {};

    for (int k0 = 0; k0 < K; k0 += BK) {
        if (sAk == 1) {
            int k4 = (tid & 3) * 4;
            int m  = tid >> 2;
            float4 v = *(const float4*)(Ab + (long)(m0 + m) * sAm + (k0 + k4));
            As[k4+0][m] = v.x; As[k4+1][m] = v.y; As[k4+2][m] = v.z; As[k4+3][m] = v.w;
        } else { // sAm == 1
            int m4 = (tid & 15) * 4;
            int k  = tid >> 4;
            float4 v = *(const float4*)(Ab + (long)(k0 + k) * sAk + (m0 + m4));
            *(float4*)&As[k][m4] = v;
        }
        if (sBn == 1) {
            int n4 = (tid & 15) * 4;
            int k  = tid >> 4;
            float4 v = *(const float4*)(Bb + (long)(k0 + k) * sBk + (n0 + n4));
            *(float4*)&Bs[k][n4] = v;
        } else { // sBk == 1
            int k4 = (tid & 3) * 4;
            int n  = tid >> 2;
            float4 v = *(const float4*)(Bb + (long)(n0 + n) * sBn + (k0 + k4));
            Bs[k4+0][n] = v.x; Bs[k4+1][n] = v.y; Bs[k4+2][n] = v.z; Bs[k4+3][n] = v.w;
        }
        __syncthreads();
#pragma unroll
        for (int kk = 0; kk < BK; ++kk) {
            float4 a = *(const float4*)&As[kk][tm * 4];
            float4 bv = *(const float4*)&Bs[kk][tn * 4];
            float av[4] = {a.x, a.y, a.z, a.w};
            float bw[4] = {bv.x, bv.y, bv.z, bv.w};
#pragma unroll
            for (int i = 0; i < 4; ++i)
#pragma unroll
                for (int j = 0; j < 4; ++j)
                    acc[i][j] = fmaf(av[i], bw[j], acc[i][j]);
        }
        __syncthreads();
    }

    float* Cb = C + (long)b * batchC;
#pragma unroll
    for (int i = 0; i < 4; ++i) {
        int row = m0 + tm * 4 + i;
        float* crow = Cb + (long)row * N + n0 + tn * 4;
        float4 o = {acc[i][0], acc[i][1], acc[i][2], acc[i][3]};
        if (bias) {
            float4 bv = *(const float4*)(bias + (long)row * N + n0 + tn * 4);
            o.x += bv.x; o.y += bv.y; o.z += bv.z; o.w += bv.w;
        }
        *(float4*)crow = o;
    }
}

// Fused: S = U @ B (U row-major [CO,K]), then logits[b,n] += sum_c w[c]*tanh(S[c,n])
__global__ __launch_bounds__(256) void logits_kernel(
    const float* __restrict__ U, const float* __restrict__ Bm,
    const float* __restrict__ w, float* __restrict__ logits,
    int N, int K, long batchU,
    int sBk, int sBn, long batchB)
{
    __shared__ float As[BK][LDT];
    __shared__ float Bs[BK][LDT];
    const int tid = threadIdx.x;
    const int b   = blockIdx.z;
    const int c0  = blockIdx.y * BM;
    const int n0  = blockIdx.x * BN;
    const float* Ab = U  + (long)b * batchU;
    const float* Bb = Bm + (long)b * batchB;
    const int tm = tid >> 4, tn = tid & 15;
    float acc[4][4] = {};

    for (int k0 = 0; k0 < K; k0 += BK) {
        {
            int k4 = (tid & 3) * 4;
            int m  = tid >> 2;
            float4 v = *(const float4*)(Ab + (long)(c0 + m) * K + (k0 + k4));
            As[k4+0][m] = v.x; As[k4+1][m] = v.y; As[k4+2][m] = v.z; As[k4+3][m] = v.w;
        }
        if (sBn == 1) {
            int n4 = (tid & 15) * 4;
            int k  = tid >> 4;
            float4 v = *(const float4*)(Bb + (long)(k0 + k) * sBk + (n0 + n4));
            *(float4*)&Bs[k][n4] = v;
        } else {
            int k4 = (tid & 3) * 4;
            int n  = tid >> 2;
            float4 v = *(const float4*)(Bb + (long)(n0 + n) * sBn + (k0 + k4));
            Bs[k4+0][n] = v.x; Bs[k4+1][n] = v.y; Bs[k4+2][n] = v.z; Bs[k4+3][n] = v.w;
        }
        __syncthreads();
#pragma unroll
        for (int kk = 0; kk < BK; ++kk) {
            float4 a = *(const float4*)&As[kk][tm * 4];
            float4 bv = *(const float4*)&Bs[kk][tn * 4];
            float av[4] = {a.x, a.y, a.z, a.w};
            float bw[4] = {bv.x, bv.y, bv.z, bv.w};
#pragma unroll
            for (int i = 0; i < 4; ++i)
#pragma unroll
                for (int j = 0; j < 4; ++j)
                    acc[i][j] = fmaf(av[i], bw[j], acc[i][j]);
        }
        __syncthreads();
    }

    // epilogue: per-column weighted tanh partial sums, reduce over the 16 thread-rows
    float wv[4];
#pragma unroll
    for (int i = 0; i < 4; ++i) wv[i] = w[c0 + tm * 4 + i];
    float cs[4];
#pragma unroll
    for (int j = 0; j < 4; ++j) {
        float s = 0.f;
#pragma unroll
        for (int i = 0; i < 4; ++i) s = fmaf(wv[i], tanhf(acc[i][j]), s);
        cs[j] = s;
    }
#pragma unroll
    for (int j = 0; j < 4; ++j) As[tm][tn * 4 + j] = cs[j];
    __syncthreads();
    if (tid < 64) {
        float s = 0.f;
#pragma unroll
        for (int r = 0; r < 16; ++r) s += As[r][tid];
        atomicAdd(logits + (long)b * N + n0 + tid, s);
    }
}

__global__ __launch_bounds__(256) void softmax_kernel(
    const float* __restrict__ lv, const float* __restrict__ lq, float* __restrict__ out)
{
    const int b = blockIdx.x;
    const int which = blockIdx.y;
    const float* x = (which == 0 ? lv : lq) + (long)b * 2048;
    float* o = out + (long)which * (Bn * 2048) + (long)b * 2048;
    const int tid = threadIdx.x;
    __shared__ float sm[4], ss[4];

    float m = -3.4e38f;
    for (int i = tid; i < 2048; i += 256) m = fmaxf(m, x[i]);
    for (int off = 32; off > 0; off >>= 1) m = fmaxf(m, __shfl_down(m, off));
    if ((tid & 63) == 0) sm[tid >> 6] = m;
    __syncthreads();
    m = fmaxf(fmaxf(sm[0], sm[1]), fmaxf(sm[2], sm[3]));

    float s = 0.f;
    for (int i = tid; i < 2048; i += 256) s += expf(x[i] - m);
    for (int off = 32; off > 0; off >>= 1) s += __shfl_down(s, off);
    if ((tid & 63) == 0) ss[tid >> 6] = s;
    __syncthreads();
    s = ss[0] + ss[1] + ss[2] + ss[3];
    float inv = 1.0f / s;
    for (int i = tid; i < 2048; i += 256) o[i] = expf(x[i] - m) * inv;
}

// v[b,h] = sum_v a_v[b,v] * V[b,h,v] — one wave per (b,h)
__global__ __launch_bounds__(256) void vout_kernel(
    const float* __restrict__ V, const float* __restrict__ av, float* __restrict__ vout)
{
    const int wave = threadIdx.x >> 6, lane = threadIdx.x & 63;
    const long idx = (long)blockIdx.x * 4 + wave;   // b*H + h
    const int b = (int)(idx >> 10);
    const int h = (int)(idx & 1023);
    const float* vp = V + ((long)b * Hd + h) * NVn;
    const float* ap = av + (long)b * NVn;
    float s = 0.f;
    for (int i = lane; i < NVn; i += 64) s = fmaf(ap[i], vp[i], s);
    for (int off = 32; off > 0; off >>= 1) s += __shfl_down(s, off);
    if (lane == 0) vout[idx] = s;
}

// q[b,h] = sum_q a_q[b,q] * Q[b,q,h] — q-split with atomics
__global__ __launch_bounds__(256) void qout_kernel(
    const float* __restrict__ Q, const float* __restrict__ aq, float* __restrict__ qout)
{
    const int h  = blockIdx.x * 256 + threadIdx.x;
    const int b  = blockIdx.z;
    const int q0 = blockIdx.y * 256;
    const float* qp = Q + (long)b * NQn * Hd;
    const float* ap = aq + (long)b * NQn + q0;
    float s = 0.f;
    for (int q = 0; q < 256; ++q) s = fmaf(ap[q], qp[(long)(q0 + q) * Hd + h], s);
    atomicAdd(qout + (long)b * Hd + h, s);
}

extern "C" void kernel_launch(void* const* d_in, const int* in_sizes, int n_in,
                              void* d_out, int out_size, void* d_ws, size_t ws_size,
                              hipStream_t stream) {
    const float* V    = (const float*)d_in[0];
    const float* Q    = (const float*)d_in[1];
    const float* W_b  = (const float*)d_in[2];
    const float* W_v  = (const float*)d_in[3];
    const float* W_q  = (const float*)d_in[4];
    const float* w_hv = (const float*)d_in[5];
    const float* w_hq = (const float*)d_in[6];
    float* out = (float*)d_out;
    float* ws  = (float*)d_ws;

    float* g  = ws;                          // B*H*H
    float* t  = g  + (long)Bn * Hd * Hd;     // B*CO*H
    float* u  = t  + (long)Bn * COn * Hd;    // B*CO*H
    float* lv = u  + (long)Bn * COn * Hd;    // B*NV
    float* lq = lv + (long)Bn * NVn;         // B*NQ

    hipMemsetAsync(lv, 0, (size_t)(Bn * NVn + Bn * NQn) * sizeof(float), stream);
    hipMemsetAsync(out + 2 * Bn * NVn + Bn * Hd, 0, (size_t)Bn * Hd * sizeof(float), stream);

    dim3 blk(256);

    // ---- Q chain: G = Q^T Q ; T = W_q@G ; U_v = W_v + T@W_b ; logits_v via U_v@V ----
    gemm_kernel<<<dim3(Hd/BN, Hd/BM, Bn), blk, 0, stream>>>(Q, Q, g, nullptr,
        Hd, Hd, NQn, 1, Hd, (long)NQn*Hd, Hd, 1, (long)NQn*Hd, (long)Hd*Hd);
    gemm_kernel<<<dim3(Hd/BN, COn/BM, Bn), blk, 0, stream>>>(W_q, g, t, nullptr,
        COn, Hd, Hd, Hd, 1, 0L, Hd, 1, (long)Hd*Hd, (long)COn*Hd);
    gemm_kernel<<<dim3(Hd/BN, COn/BM, Bn), blk, 0, stream>>>(t, W_b, u, W_v,
        COn, Hd, Hd, Hd, 1, (long)COn*Hd, Hd, 1, 0L, (long)COn*Hd);
    logits_kernel<<<dim3(NVn/BN, COn/BM, Bn), blk, 0, stream>>>(u, V, w_hv, lv,
        NVn, Hd, (long)COn*Hd, NVn, 1, (long)Hd*NVn);

    // ---- V chain: G = V V^T ; T = W_v@G ; U_q = W_q + T@W_b^T ; logits_q via U_q@Q^T ----
    gemm_kernel<<<dim3(Hd/BN, Hd/BM, Bn), blk, 0, stream>>>(V, V, g, nullptr,
        Hd, Hd, NVn, NVn, 1, (long)Hd*NVn, 1, NVn, (long)Hd*NVn, (long)Hd*Hd);
    gemm_kernel<<<dim3(Hd/BN, COn/BM, Bn), blk, 0, stream>>>(W_v, g, t, nullptr,
        COn, Hd, Hd, Hd, 1, 0L, Hd, 1, (long)Hd*Hd, (long)COn*Hd);
    gemm_kernel<<<dim3(Hd/BN, COn/BM, Bn), blk, 0, stream>>>(t, W_b, u, W_q,
        COn, Hd, Hd, Hd, 1, (long)COn*Hd, 1, Hd, 0L, (long)COn*Hd);
    logits_kernel<<<dim3(NQn/BN, COn/BM, Bn), blk, 0, stream>>>(u, Q, w_hq, lq,
        NQn, Hd, (long)COn*Hd, 1, Hd, (long)NQn*Hd);

    // ---- softmax + outputs ----
    softmax_kernel<<<dim3(Bn, 2), blk, 0, stream>>>(lv, lq, out);
    vout_kernel<<<dim3(Bn * Hd / 4), blk, 0, stream>>>(V, out, out + 2 * Bn * NVn);
    qout_kernel<<<dim3(Hd/256, NQn/256, Bn), blk, 0, stream>>>(Q, out + Bn * NVn,
        out + 2 * Bn * NVn + Bn * Hd);
}

// Round 3
// 3619.403 us; speedup vs baseline: 1.1341x; 1.1341x over previous
//
#include <hip/hip_runtime.h>
#include <math.h>

#define Bn  16
#define Hd  1024
#define COn 512
#define NVn 2048
#define NQn 2048

#define BM 128
#define BN 128
#define BK 16
#define LDT 132   // 132 % 32 == 4: rows shift banks, staging writes <=2-way (free)

__device__ __forceinline__ float fast_tanh(float x) {
    float ax = fabsf(x);
    float e  = __expf(2.0f * ax);          // inf for large ax -> t = 1
    float t  = 1.0f - 2.0f / (e + 1.0f);
    return copysignf(t, x);
}

// Generic stride-parameterized fp32 GEMM: C[m,n] = sum_k A[m*sAm+k*sAk]*B[k*sBk+n*sBn] (+bias)
// M,N multiples of 128; K multiple of 16. Exactly one of (sAk==1, sAm==1) and
// one of (sBn==1, sBk==1) must hold. If LOGITS: instead of writing C, computes
// logits[b,n] += sum_m w[m]*tanh(S[m,n]).
template <bool LOGITS>
__global__ __launch_bounds__(256) void gemm_core(
    const float* __restrict__ A, const float* __restrict__ Bm, float* __restrict__ C,
    const float* __restrict__ bias,
    int M, int N, int K,
    int sAm, int sAk, long batchA,
    int sBk, int sBn, long batchB,
    long batchC,
    const float* __restrict__ w, float* __restrict__ logits)
{
    __shared__ float As[BK][LDT];
    __shared__ float Bs[BK][LDT];
    const int tid = threadIdx.x;
    const int b   = blockIdx.z;
    const int m0  = blockIdx.y * BM;
    const int n0  = blockIdx.x * BN;
    const float* Ab = A  + (long)b * batchA;
    const float* Bb = Bm + (long)b * batchB;
    const int tm = tid >> 4, tn = tid & 15;
    float acc[8][8] = {};

    for (int k0 = 0; k0 < K; k0 += BK) {
        if (sAk == 1) {
#pragma unroll
            for (int i = 0; i < 2; ++i) {
                int idx = tid + i * 256;          // 512 float4s: 128 m x 4 k-groups
                int m = idx >> 2, kg = (idx & 3) * 4;
                float4 v = *(const float4*)(Ab + (long)(m0 + m) * sAm + k0 + kg);
                As[kg+0][m] = v.x; As[kg+1][m] = v.y; As[kg+2][m] = v.z; As[kg+3][m] = v.w;
            }
        } else { // sAm == 1
#pragma unroll
            for (int i = 0; i < 2; ++i) {
                int idx = tid + i * 256;          // 16 k x 32 m-groups
                int k = idx >> 5, mg = (idx & 31) * 4;
                float4 v = *(const float4*)(Ab + (long)(k0 + k) * sAk + m0 + mg);
                *(float4*)&As[k][mg] = v;
            }
        }
        if (sBn == 1) {
#pragma unroll
            for (int i = 0; i < 2; ++i) {
                int idx = tid + i * 256;
                int k = idx >> 5, ng = (idx & 31) * 4;
                float4 v = *(const float4*)(Bb + (long)(k0 + k) * sBk + n0 + ng);
                *(float4*)&Bs[k][ng] = v;
            }
        } else { // sBk == 1
#pragma unroll
            for (int i = 0; i < 2; ++i) {
                int idx = tid + i * 256;
                int n = idx >> 2, kg = (idx & 3) * 4;
                float4 v = *(const float4*)(Bb + (long)(n0 + n) * sBn + k0 + kg);
                Bs[kg+0][n] = v.x; Bs[kg+1][n] = v.y; Bs[kg+2][n] = v.z; Bs[kg+3][n] = v.w;
            }
        }
        __syncthreads();
#pragma unroll
        for (int kk = 0; kk < BK; ++kk) {
            float a[8], bv[8];
            *(float4*)&a[0]  = *(const float4*)&As[kk][tm * 8];
            *(float4*)&a[4]  = *(const float4*)&As[kk][tm * 8 + 4];
            *(float4*)&bv[0] = *(const float4*)&Bs[kk][tn * 8];
            *(float4*)&bv[4] = *(const float4*)&Bs[kk][tn * 8 + 4];
#pragma unroll
            for (int i = 0; i < 8; ++i)
#pragma unroll
                for (int j = 0; j < 8; ++j)
                    acc[i][j] = fmaf(a[i], bv[j], acc[i][j]);
        }
        __syncthreads();
    }

    if constexpr (!LOGITS) {
        float* Cb = C + (long)b * batchC;
#pragma unroll
        for (int i = 0; i < 8; ++i) {
            int row = m0 + tm * 8 + i;
            float* crow = Cb + (long)row * N + n0 + tn * 8;
            float4 o0 = {acc[i][0], acc[i][1], acc[i][2], acc[i][3]};
            float4 o1 = {acc[i][4], acc[i][5], acc[i][6], acc[i][7]};
            if (bias) {
                const float* brow = bias + (long)row * N + n0 + tn * 8;
                float4 b0 = *(const float4*)brow;
                float4 b1 = *(const float4*)(brow + 4);
                o0.x += b0.x; o0.y += b0.y; o0.z += b0.z; o0.w += b0.w;
                o1.x += b1.x; o1.y += b1.y; o1.z += b1.z; o1.w += b1.w;
            }
            *(float4*)crow = o0;
            *(float4*)(crow + 4) = o1;
        }
    } else {
        float wv[8];
#pragma unroll
        for (int i = 0; i < 8; ++i) wv[i] = w[m0 + tm * 8 + i];
        float cs[8];
#pragma unroll
        for (int j = 0; j < 8; ++j) {
            float s = 0.f;
#pragma unroll
            for (int i = 0; i < 8; ++i) s = fmaf(wv[i], fast_tanh(acc[i][j]), s);
            cs[j] = s;
        }
        __syncthreads();   // main loop done; reuse As for the 16-row reduction
        *(float4*)&As[tm][tn * 8]     = *(float4*)&cs[0];
        *(float4*)&As[tm][tn * 8 + 4] = *(float4*)&cs[4];
        __syncthreads();
        if (tid < 128) {
            float s = 0.f;
#pragma unroll
            for (int r = 0; r < 16; ++r) s += As[r][tid];
            atomicAdd(logits + (long)b * N + n0 + tid, s);
        }
    }
}

__global__ __launch_bounds__(256) void softmax_kernel(
    const float* __restrict__ lv, const float* __restrict__ lq, float* __restrict__ out)
{
    const int b = blockIdx.x;
    const int which = blockIdx.y;
    const float* x = (which == 0 ? lv : lq) + (long)b * 2048;
    float* o = out + (long)which * (Bn * 2048) + (long)b * 2048;
    const int tid = threadIdx.x;
    __shared__ float sm[4], ss[4];

    float m = -3.4e38f;
    for (int i = tid; i < 2048; i += 256) m = fmaxf(m, x[i]);
    for (int off = 32; off > 0; off >>= 1) m = fmaxf(m, __shfl_down(m, off));
    if ((tid & 63) == 0) sm[tid >> 6] = m;
    __syncthreads();
    m = fmaxf(fmaxf(sm[0], sm[1]), fmaxf(sm[2], sm[3]));

    float s = 0.f;
    for (int i = tid; i < 2048; i += 256) s += expf(x[i] - m);
    for (int off = 32; off > 0; off >>= 1) s += __shfl_down(s, off);
    if ((tid & 63) == 0) ss[tid >> 6] = s;
    __syncthreads();
    s = ss[0] + ss[1] + ss[2] + ss[3];
    float inv = 1.0f / s;
    for (int i = tid; i < 2048; i += 256) o[i] = expf(x[i] - m) * inv;
}

// v[b,h] = sum_v a_v[b,v] * V[b,h,v] — one wave per (b,h)
__global__ __launch_bounds__(256) void vout_kernel(
    const float* __restrict__ V, const float* __restrict__ av, float* __restrict__ vout)
{
    const int wave = threadIdx.x >> 6, lane = threadIdx.x & 63;
    const long idx = (long)blockIdx.x * 4 + wave;   // b*H + h
    const int b = (int)(idx >> 10);
    const int h = (int)(idx & 1023);
    const float* vp = V + ((long)b * Hd + h) * NVn;
    const float* ap = av + (long)b * NVn;
    float s = 0.f;
    for (int i = lane; i < NVn; i += 64) s = fmaf(ap[i], vp[i], s);
    for (int off = 32; off > 0; off >>= 1) s += __shfl_down(s, off);
    if (lane == 0) vout[idx] = s;
}

// q[b,h] = sum_q a_q[b,q] * Q[b,q,h] — q-split with atomics
__global__ __launch_bounds__(256) void qout_kernel(
    const float* __restrict__ Q, const float* __restrict__ aq, float* __restrict__ qout)
{
    const int h  = blockIdx.x * 256 + threadIdx.x;
    const int b  = blockIdx.z;
    const int q0 = blockIdx.y * 256;
    const float* qp = Q + (long)b * NQn * Hd;
    const float* ap = aq + (long)b * NQn + q0;
    float s = 0.f;
    for (int q = 0; q < 256; ++q) s = fmaf(ap[q], qp[(long)(q0 + q) * Hd + h], s);
    atomicAdd(qout + (long)b * Hd + h, s);
}

extern "C" void kernel_launch(void* const* d_in, const int* in_sizes, int n_in,
                              void* d_out, int out_size, void* d_ws, size_t ws_size,
                              hipStream_t stream) {
    const float* V    = (const float*)d_in[0];
    const float* Q    = (const float*)d_in[1];
    const float* W_b  = (const float*)d_in[2];
    const float* W_v  = (const float*)d_in[3];
    const float* W_q  = (const float*)d_in[4];
    const float* w_hv = (const float*)d_in[5];
    const float* w_hq = (const float*)d_in[6];
    float* out = (float*)d_out;
    float* ws  = (float*)d_ws;

    float* g  = ws;                          // B*H*H
    float* t  = g  + (long)Bn * Hd * Hd;     // B*CO*H
    float* u  = t  + (long)Bn * COn * Hd;    // B*CO*H
    float* lv = u  + (long)Bn * COn * Hd;    // B*NV
    float* lq = lv + (long)Bn * NVn;         // B*NQ

    hipMemsetAsync(lv, 0, (size_t)(Bn * NVn + Bn * NQn) * sizeof(float), stream);
    hipMemsetAsync(out + 2 * Bn * NVn + Bn * Hd, 0, (size_t)Bn * Hd * sizeof(float), stream);

    dim3 blk(256);

    // ---- Q chain: G = Q^T Q ; T = W_q@G ; U_v = W_v + T@W_b ; logits_v via U_v@V ----
    gemm_core<false><<<dim3(Hd/BN, Hd/BM, Bn), blk, 0, stream>>>(Q, Q, g, nullptr,
        Hd, Hd, NQn, 1, Hd, (long)NQn*Hd, Hd, 1, (long)NQn*Hd, (long)Hd*Hd, nullptr, nullptr);
    gemm_core<false><<<dim3(Hd/BN, COn/BM, Bn), blk, 0, stream>>>(W_q, g, t, nullptr,
        COn, Hd, Hd, Hd, 1, 0L, Hd, 1, (long)Hd*Hd, (long)COn*Hd, nullptr, nullptr);
    gemm_core<false><<<dim3(Hd/BN, COn/BM, Bn), blk, 0, stream>>>(t, W_b, u, W_v,
        COn, Hd, Hd, Hd, 1, (long)COn*Hd, Hd, 1, 0L, (long)COn*Hd, nullptr, nullptr);
    gemm_core<true><<<dim3(NVn/BN, COn/BM, Bn), blk, 0, stream>>>(
        /*A=*/u, /*B=*/V, /*C=*/nullptr, /*bias=*/nullptr,
        /*M=*/COn, /*N=*/NVn, /*K=*/Hd,
        /*sAm=*/Hd, /*sAk=*/1, /*batchA=*/(long)COn*Hd,
        /*sBk=*/NVn, /*sBn=*/1, /*batchB=*/(long)Hd*NVn,
        /*batchC=*/0L, /*w=*/w_hv, /*logits=*/lv);

    // ---- V chain: G = V V^T ; T = W_v@G ; U_q = W_q + T@W_b^T ; logits_q via U_q@Q^T ----
    gemm_core<false><<<dim3(Hd/BN, Hd/BM, Bn), blk, 0, stream>>>(V, V, g, nullptr,
        Hd, Hd, NVn, NVn, 1, (long)Hd*NVn, 1, NVn, (long)Hd*NVn, (long)Hd*Hd, nullptr, nullptr);
    gemm_core<false><<<dim3(Hd/BN, COn/BM, Bn), blk, 0, stream>>>(W_v, g, t, nullptr,
        COn, Hd, Hd, Hd, 1, 0L, Hd, 1, (long)Hd*Hd, (long)COn*Hd, nullptr, nullptr);
    gemm_core<false><<<dim3(Hd/BN, COn/BM, Bn), blk, 0, stream>>>(t, W_b, u, W_q,
        COn, Hd, Hd, Hd, 1, (long)COn*Hd, 1, Hd, 0L, (long)COn*Hd, nullptr, nullptr);
    gemm_core<true><<<dim3(NQn/BN, COn/BM, Bn), blk, 0, stream>>>(
        /*A=*/u, /*B=*/Q, /*C=*/nullptr, /*bias=*/nullptr,
        /*M=*/COn, /*N=*/NQn, /*K=*/Hd,
        /*sAm=*/Hd, /*sAk=*/1, /*batchA=*/(long)COn*Hd,
        /*sBk=*/1, /*sBn=*/Hd, /*batchB=*/(long)NQn*Hd,
        /*batchC=*/0L, /*w=*/w_hq, /*logits=*/lq);

    // ---- softmax + outputs ----
    softmax_kernel<<<dim3(Bn, 2), blk, 0, stream>>>(lv, lq, out);
    vout_kernel<<<dim3(Bn * Hd / 4), blk, 0, stream>>>(V, out, out + 2 * Bn * NVn);
    qout_kernel<<<dim3(Hd/256, NQn/256, Bn), blk, 0, stream>>>(Q, out + Bn * NVn,
        out + 2 * Bn * NVn + Bn * Hd);
}

// Round 4
// 2578.693 us; speedup vs baseline: 1.5918x; 1.4036x over previous
//
#include <hip/hip_runtime.h>
#include <math.h>

#define Bn  16
#define Hd  1024
#define COn 512
#define NVn 2048
#define NQn 2048

#define BM 128
#define BN 128
#define BK 16
#define LDT 132

typedef unsigned short u16;
typedef __attribute__((ext_vector_type(8))) short short8;
typedef __attribute__((ext_vector_type(4))) float floatx4;

__device__ __forceinline__ float fast_tanh(float x) {
    float ax = fabsf(x);
    float e  = __expf(2.0f * ax);
    float t  = 1.0f - 2.0f / (e + 1.0f);
    return copysignf(t, x);
}

__device__ __forceinline__ u16 f32_to_bf16(float x) {
    unsigned u = __float_as_uint(x);
    unsigned r = (u + 0x7fffu + ((u >> 16) & 1u)) >> 16;   // RNE, finite inputs
    return (u16)r;
}
__device__ __forceinline__ float bf16_to_f32(u16 h) {
    return __uint_as_float(((unsigned)h) << 16);
}

// ---------------- fp32 GEMM (mid + logits stages) ----------------
// C[m,n] = sum_k A[m*sAm+k*sAk]*B[k*sBk+n*sBn] (+bias). 8x8/thread as 2x(4+4)
// split 64 apart: fragment reads cover 64 consecutive floats -> conflict-free.
template <bool LOGITS>
__global__ __launch_bounds__(256) void gemm_core(
    const float* __restrict__ A, const float* __restrict__ Bm, float* __restrict__ C,
    const float* __restrict__ bias,
    int M, int N, int K,
    int sAm, int sAk, long batchA,
    int sBk, int sBn, long batchB,
    long batchC,
    const float* __restrict__ w, float* __restrict__ logits)
{
    __shared__ float As[BK][LDT];
    __shared__ float Bs[BK][LDT];
    const int tid = threadIdx.x;
    const int b   = blockIdx.z;
    const int m0  = blockIdx.y * BM;
    const int n0  = blockIdx.x * BN;
    const float* Ab = A  + (long)b * batchA;
    const float* Bb = Bm + (long)b * batchB;
    const int tm = tid >> 4, tn = tid & 15;
    float acc[8][8] = {};

    for (int k0 = 0; k0 < K; k0 += BK) {
        if (sAk == 1) {
#pragma unroll
            for (int i = 0; i < 2; ++i) {
                int idx = tid + i * 256;
                int m = idx >> 2, kg = (idx & 3) * 4;
                float4 v = *(const float4*)(Ab + (long)(m0 + m) * sAm + k0 + kg);
                As[kg+0][m] = v.x; As[kg+1][m] = v.y; As[kg+2][m] = v.z; As[kg+3][m] = v.w;
            }
        } else {
#pragma unroll
            for (int i = 0; i < 2; ++i) {
                int idx = tid + i * 256;
                int k = idx >> 5, mg = (idx & 31) * 4;
                float4 v = *(const float4*)(Ab + (long)(k0 + k) * sAk + m0 + mg);
                *(float4*)&As[k][mg] = v;
            }
        }
        if (sBn == 1) {
#pragma unroll
            for (int i = 0; i < 2; ++i) {
                int idx = tid + i * 256;
                int k = idx >> 5, ng = (idx & 31) * 4;
                float4 v = *(const float4*)(Bb + (long)(k0 + k) * sBk + n0 + ng);
                *(float4*)&Bs[k][ng] = v;
            }
        } else {
#pragma unroll
            for (int i = 0; i < 2; ++i) {
                int idx = tid + i * 256;
                int n = idx >> 2, kg = (idx & 3) * 4;
                float4 v = *(const float4*)(Bb + (long)(n0 + n) * sBn + k0 + kg);
                Bs[kg+0][n] = v.x; Bs[kg+1][n] = v.y; Bs[kg+2][n] = v.z; Bs[kg+3][n] = v.w;
            }
        }
        __syncthreads();
#pragma unroll
        for (int kk = 0; kk < BK; ++kk) {
            float a[8], bv[8];
            *(float4*)&a[0]  = *(const float4*)&As[kk][tm * 4];
            *(float4*)&a[4]  = *(const float4*)&As[kk][64 + tm * 4];
            *(float4*)&bv[0] = *(const float4*)&Bs[kk][tn * 4];
            *(float4*)&bv[4] = *(const float4*)&Bs[kk][64 + tn * 4];
#pragma unroll
            for (int i = 0; i < 8; ++i)
#pragma unroll
                for (int j = 0; j < 8; ++j)
                    acc[i][j] = fmaf(a[i], bv[j], acc[i][j]);
        }
        __syncthreads();
    }

    if constexpr (!LOGITS) {
        float* Cb = C + (long)b * batchC;
#pragma unroll
        for (int i = 0; i < 8; ++i) {
            int row = m0 + (i >> 2) * 64 + tm * 4 + (i & 3);
            float* crow = Cb + (long)row * N + n0;
            float4 o0 = {acc[i][0], acc[i][1], acc[i][2], acc[i][3]};
            float4 o1 = {acc[i][4], acc[i][5], acc[i][6], acc[i][7]};
            if (bias) {
                const float* brow = bias + (long)row * N + n0;
                float4 b0 = *(const float4*)(brow + tn * 4);
                float4 b1 = *(const float4*)(brow + 64 + tn * 4);
                o0.x += b0.x; o0.y += b0.y; o0.z += b0.z; o0.w += b0.w;
                o1.x += b1.x; o1.y += b1.y; o1.z += b1.z; o1.w += b1.w;
            }
            *(float4*)(crow + tn * 4) = o0;
            *(float4*)(crow + 64 + tn * 4) = o1;
        }
    } else {
        float wv[8];
#pragma unroll
        for (int i = 0; i < 8; ++i) wv[i] = w[m0 + (i >> 2) * 64 + tm * 4 + (i & 3)];
        float cs[8];
#pragma unroll
        for (int j = 0; j < 8; ++j) {
            float s = 0.f;
#pragma unroll
            for (int i = 0; i < 8; ++i) s = fmaf(wv[i], fast_tanh(acc[i][j]), s);
            cs[j] = s;
        }
        __syncthreads();
        *(float4*)&As[tm][tn * 4]      = *(float4*)&cs[0];
        *(float4*)&As[tm][64 + tn * 4] = *(float4*)&cs[4];
        __syncthreads();
        if (tid < 128) {
            float s = 0.f;
#pragma unroll
            for (int r = 0; r < 16; ++r) s += As[r][tid];
            atomicAdd(logits + (long)b * N + n0 + tid, s);
        }
    }
}

// ---------------- bf16 split conversions ----------------
// V [B,H,NV]: elementwise split, layout preserved (already k-contiguous).
__global__ __launch_bounds__(256) void split_kernel(
    const float* __restrict__ X, u16* __restrict__ Xh, u16* __restrict__ Xl)
{
    long i0 = ((long)blockIdx.x * 256 + threadIdx.x) * 4;
    float4 v = *(const float4*)(X + i0);
    float xs[4] = {v.x, v.y, v.z, v.w};
    u16 h[4], l[4];
#pragma unroll
    for (int i = 0; i < 4; ++i) {
        h[i] = f32_to_bf16(xs[i]);
        l[i] = f32_to_bf16(xs[i] - bf16_to_f32(h[i]));
    }
    *(ushort4*)(Xh + i0) = *(ushort4*)h;
    *(ushort4*)(Xl + i0) = *(ushort4*)l;
}

// Q [B,NQ,H] -> QT hi/lo [B,H,NQ] (transpose + split), 64x64 LDS tiles.
__global__ __launch_bounds__(256) void tsplit_kernel(
    const float* __restrict__ Q, u16* __restrict__ Th, u16* __restrict__ Tl)
{
    __shared__ float tile[64][65];
    const int b = blockIdx.z, q0 = blockIdx.x * 64, h0 = blockIdx.y * 64;
    const float* Qb = Q + (long)b * NQn * Hd;
    const int t = threadIdx.x;
    const int r = t >> 2, c0 = (t & 3) * 16;
#pragma unroll
    for (int i = 0; i < 4; ++i)
        *(float4*)&tile[r][c0 + i * 4] =
            *(const float4*)(Qb + (long)(q0 + r) * Hd + h0 + c0 + i * 4);
    __syncthreads();
    const int h = r, v0 = c0;
    u16 hbuf[16], lbuf[16];
#pragma unroll
    for (int i = 0; i < 16; ++i) {
        float x = tile[v0 + i][h];
        u16 hi = f32_to_bf16(x);
        hbuf[i] = hi;
        lbuf[i] = f32_to_bf16(x - bf16_to_f32(hi));
    }
    long o = (long)b * Hd * NQn + (long)(h0 + h) * NQn + q0 + v0;
    *(short8*)(Th + o)     = *(short8*)&hbuf[0];
    *(short8*)(Th + o + 8) = *(short8*)&hbuf[8];
    *(short8*)(Tl + o)     = *(short8*)&lbuf[0];
    *(short8*)(Tl + o + 8) = *(short8*)&lbuf[8];
}

// ---------------- bf16x3 MFMA gram: G[b] = T T^T, T = [Hd, NVn] k-contiguous ----
// 128x128 tile, 4 waves in 2x2, each wave 4x4 of 16x16x32 MFMA, 3 products/pair.
__global__ __launch_bounds__(256) void gram_mfma(
    const u16* __restrict__ Th, const u16* __restrict__ Tl, float* __restrict__ G)
{
    __shared__ u16 Ah[128 * 32], Al[128 * 32], Bh[128 * 32], Bl[128 * 32];
    const int b = blockIdx.z, m0 = blockIdx.y * 128, n0 = blockIdx.x * 128;
    const long base = (long)b * Hd * NVn;
    const u16* Thb = Th + base;
    const u16* Tlb = Tl + base;
    const int tid = threadIdx.x;
    const int wave = tid >> 6, lane = tid & 63, quad = lane >> 4, l16 = lane & 15;
    const int wm = (wave >> 1) * 64, wn = (wave & 1) * 64;
    floatx4 acc[4][4] = {};

    for (int k0 = 0; k0 < NVn; k0 += 32) {
#pragma unroll
        for (int i = 0; i < 2; ++i) {
            int c = i * 256 + tid;
            int row = c >> 2, ko = (c & 3) * 8;
            long ga = (long)(m0 + row) * NVn + k0 + ko;
            long gb = (long)(n0 + row) * NVn + k0 + ko;
            *(short8*)&Ah[row * 32 + ko] = *(const short8*)&Thb[ga];
            *(short8*)&Al[row * 32 + ko] = *(const short8*)&Tlb[ga];
            *(short8*)&Bh[row * 32 + ko] = *(const short8*)&Thb[gb];
            *(short8*)&Bl[row * 32 + ko] = *(const short8*)&Tlb[gb];
        }
        __syncthreads();
        short8 ah[4], al[4], bh[4], bl[4];
#pragma unroll
        for (int t4 = 0; t4 < 4; ++t4) {
            int am = wm + t4 * 16 + l16;
            ah[t4] = *(const short8*)&Ah[am * 32 + quad * 8];
            al[t4] = *(const short8*)&Al[am * 32 + quad * 8];
            int bn = wn + t4 * 16 + l16;
            bh[t4] = *(const short8*)&Bh[bn * 32 + quad * 8];
            bl[t4] = *(const short8*)&Bl[bn * 32 + quad * 8];
        }
#pragma unroll
        for (int mt = 0; mt < 4; ++mt)
#pragma unroll
            for (int nt = 0; nt < 4; ++nt) {
                floatx4 a0 = acc[mt][nt];
                a0 = __builtin_amdgcn_mfma_f32_16x16x32_bf16(ah[mt], bh[nt], a0, 0, 0, 0);
                a0 = __builtin_amdgcn_mfma_f32_16x16x32_bf16(ah[mt], bl[nt], a0, 0, 0, 0);
                a0 = __builtin_amdgcn_mfma_f32_16x16x32_bf16(al[mt], bh[nt], a0, 0, 0, 0);
                acc[mt][nt] = a0;
            }
        __syncthreads();
    }
    float* Gb = G + (long)b * Hd * Hd;
#pragma unroll
    for (int mt = 0; mt < 4; ++mt)
#pragma unroll
        for (int nt = 0; nt < 4; ++nt)
#pragma unroll
            for (int r = 0; r < 4; ++r) {
                int row = m0 + wm + mt * 16 + quad * 4 + r;
                int col = n0 + wn + nt * 16 + l16;
                Gb[(long)row * Hd + col] = acc[mt][nt][r];
            }
}

// ---------------- small kernels ----------------
__global__ __launch_bounds__(256) void softmax_kernel(
    const float* __restrict__ lv, const float* __restrict__ lq, float* __restrict__ out)
{
    const int b = blockIdx.x;
    const int which = blockIdx.y;
    const float* x = (which == 0 ? lv : lq) + (long)b * 2048;
    float* o = out + (long)which * (Bn * 2048) + (long)b * 2048;
    const int tid = threadIdx.x;
    __shared__ float sm[4], ss[4];

    float m = -3.4e38f;
    for (int i = tid; i < 2048; i += 256) m = fmaxf(m, x[i]);
    for (int off = 32; off > 0; off >>= 1) m = fmaxf(m, __shfl_down(m, off));
    if ((tid & 63) == 0) sm[tid >> 6] = m;
    __syncthreads();
    m = fmaxf(fmaxf(sm[0], sm[1]), fmaxf(sm[2], sm[3]));

    float s = 0.f;
    for (int i = tid; i < 2048; i += 256) s += expf(x[i] - m);
    for (int off = 32; off > 0; off >>= 1) s += __shfl_down(s, off);
    if ((tid & 63) == 0) ss[tid >> 6] = s;
    __syncthreads();
    s = ss[0] + ss[1] + ss[2] + ss[3];
    float inv = 1.0f / s;
    for (int i = tid; i < 2048; i += 256) o[i] = expf(x[i] - m) * inv;
}

__global__ __launch_bounds__(256) void vout_kernel(
    const float* __restrict__ V, const float* __restrict__ av, float* __restrict__ vout)
{
    const int wave = threadIdx.x >> 6, lane = threadIdx.x & 63;
    const long idx = (long)blockIdx.x * 4 + wave;
    const int b = (int)(idx >> 10);
    const int h = (int)(idx & 1023);
    const float* vp = V + ((long)b * Hd + h) * NVn;
    const float* ap = av + (long)b * NVn;
    float s = 0.f;
    for (int i = lane; i < NVn; i += 64) s = fmaf(ap[i], vp[i], s);
    for (int off = 32; off > 0; off >>= 1) s += __shfl_down(s, off);
    if (lane == 0) vout[idx] = s;
}

__global__ __launch_bounds__(256) void qout_kernel(
    const float* __restrict__ Q, const float* __restrict__ aq, float* __restrict__ qout)
{
    const int h  = blockIdx.x * 256 + threadIdx.x;
    const int b  = blockIdx.z;
    const int q0 = blockIdx.y * 256;
    const float* qp = Q + (long)b * NQn * Hd;
    const float* ap = aq + (long)b * NQn + q0;
    float s = 0.f;
    for (int q = 0; q < 256; ++q) s = fmaf(ap[q], qp[(long)(q0 + q) * Hd + h], s);
    atomicAdd(qout + (long)b * Hd + h, s);
}

extern "C" void kernel_launch(void* const* d_in, const int* in_sizes, int n_in,
                              void* d_out, int out_size, void* d_ws, size_t ws_size,
                              hipStream_t stream) {
    const float* V    = (const float*)d_in[0];
    const float* Q    = (const float*)d_in[1];
    const float* W_b  = (const float*)d_in[2];
    const float* W_v  = (const float*)d_in[3];
    const float* W_q  = (const float*)d_in[4];
    const float* w_hv = (const float*)d_in[5];
    const float* w_hq = (const float*)d_in[6];
    float* out = (float*)d_out;
    float* ws  = (float*)d_ws;

    const long g_elems  = (long)Bn * Hd * Hd;       // 16.8M f32
    const long tu_elems = (long)Bn * COn * Hd;      // 8.4M f32 each
    const long bf_elems = (long)Bn * Hd * NVn;      // 33.6M u16 each (hi or lo)

    // bf16 layout: [g | R(=134MB: t,u alias + hi/lo bf16) | lv | lq]
    const size_t need_bf16 = (size_t)g_elems * 4 + (size_t)bf_elems * 2 * 2
                           + (size_t)(Bn * NVn + Bn * NQn) * 4;
    const bool use_mfma = ws_size >= need_bf16;

    float* g  = ws;
    float* t  = g + g_elems;
    float* u  = t + tu_elems;
    float *lv, *lq;
    u16 *bh = nullptr, *bl = nullptr;
    if (use_mfma) {
        bh = (u16*)t;                  // R region starts at t
        bl = bh + bf_elems;
        lv = (float*)(bh + 2 * bf_elems);
        lq = lv + Bn * NVn;
    } else {
        lv = u + tu_elems;
        lq = lv + Bn * NVn;
    }

    hipMemsetAsync(lv, 0, (size_t)(Bn * NVn + Bn * NQn) * sizeof(float), stream);
    hipMemsetAsync(out + 2 * Bn * NVn + Bn * Hd, 0, (size_t)Bn * Hd * sizeof(float), stream);

    dim3 blk(256);

    // ---- Q chain: G = Q^T Q ; T = W_q@G ; U_v = W_v + T@W_b ; logits_v ----
    if (use_mfma) {
        tsplit_kernel<<<dim3(NQn / 64, Hd / 64, Bn), blk, 0, stream>>>(Q, bh, bl);
        gram_mfma<<<dim3(Hd / 128, Hd / 128, Bn), blk, 0, stream>>>(bh, bl, g);
    } else {
        gemm_core<false><<<dim3(Hd/BN, Hd/BM, Bn), blk, 0, stream>>>(Q, Q, g, nullptr,
            Hd, Hd, NQn, 1, Hd, (long)NQn*Hd, Hd, 1, (long)NQn*Hd, (long)Hd*Hd, nullptr, nullptr);
    }
    gemm_core<false><<<dim3(Hd/BN, COn/BM, Bn), blk, 0, stream>>>(W_q, g, t, nullptr,
        COn, Hd, Hd, Hd, 1, 0L, Hd, 1, (long)Hd*Hd, (long)COn*Hd, nullptr, nullptr);
    gemm_core<false><<<dim3(Hd/BN, COn/BM, Bn), blk, 0, stream>>>(t, W_b, u, W_v,
        COn, Hd, Hd, Hd, 1, (long)COn*Hd, Hd, 1, 0L, (long)COn*Hd, nullptr, nullptr);
    gemm_core<true><<<dim3(NVn/BN, COn/BM, Bn), blk, 0, stream>>>(
        u, V, nullptr, nullptr, COn, NVn, Hd,
        /*sAm=*/Hd, /*sAk=*/1, /*batchA=*/(long)COn*Hd,
        /*sBk=*/NVn, /*sBn=*/1, /*batchB=*/(long)Hd*NVn,
        /*batchC=*/0L, w_hv, lv);

    // ---- V chain: G = V V^T ; T = W_v@G ; U_q = W_q + T@W_b^T ; logits_q ----
    if (use_mfma) {
        split_kernel<<<dim3((unsigned)(bf_elems / 1024)), blk, 0, stream>>>(V, bh, bl);
        gram_mfma<<<dim3(Hd / 128, Hd / 128, Bn), blk, 0, stream>>>(bh, bl, g);
    } else {
        gemm_core<false><<<dim3(Hd/BN, Hd/BM, Bn), blk, 0, stream>>>(V, V, g, nullptr,
            Hd, Hd, NVn, NVn, 1, (long)Hd*NVn, 1, NVn, (long)Hd*NVn, (long)Hd*Hd, nullptr, nullptr);
    }
    gemm_core<false><<<dim3(Hd/BN, COn/BM, Bn), blk, 0, stream>>>(W_v, g, t, nullptr,
        COn, Hd, Hd, Hd, 1, 0L, Hd, 1, (long)Hd*Hd, (long)COn*Hd, nullptr, nullptr);
    gemm_core<false><<<dim3(Hd/BN, COn/BM, Bn), blk, 0, stream>>>(t, W_b, u, W_q,
        COn, Hd, Hd, Hd, 1, (long)COn*Hd, 1, Hd, 0L, (long)COn*Hd, nullptr, nullptr);
    gemm_core<true><<<dim3(NQn/BN, COn/BM, Bn), blk, 0, stream>>>(
        u, Q, nullptr, nullptr, COn, NQn, Hd,
        /*sAm=*/Hd, /*sAk=*/1, /*batchA=*/(long)COn*Hd,
        /*sBk=*/1, /*sBn=*/Hd, /*batchB=*/(long)NQn*Hd,
        /*batchC=*/0L, w_hq, lq);

    // ---- softmax + outputs ----
    softmax_kernel<<<dim3(Bn, 2), blk, 0, stream>>>(lv, lq, out);
    vout_kernel<<<dim3(Bn * Hd / 4), blk, 0, stream>>>(V, out, out + 2 * Bn * NVn);
    qout_kernel<<<dim3(Hd/256, NQn/256, Bn), blk, 0, stream>>>(Q, out + Bn * NVn,
        out + 2 * Bn * NVn + Bn * Hd);
}

// Round 5
// 1458.055 us; speedup vs baseline: 2.8152x; 1.7686x over previous
//
#include <hip/hip_runtime.h>
#include <math.h>

#define Bn  16
#define Hd  1024
#define COn 512
#define NVn 2048
#define NQn 2048

#define BM 128
#define BN 128
#define BK 16
#define LDT 132

typedef unsigned short u16;
typedef __attribute__((ext_vector_type(8))) short short8;
typedef __attribute__((ext_vector_type(4))) float floatx4;

__device__ __forceinline__ float fast_tanh(float x) {
    float ax = fabsf(x);
    float e  = __expf(2.0f * ax);
    float t  = 1.0f - 2.0f / (e + 1.0f);
    return copysignf(t, x);
}

__device__ __forceinline__ u16 f32_to_bf16(float x) {
    unsigned u = __float_as_uint(x);
    unsigned r = (u + 0x7fffu + ((u >> 16) & 1u)) >> 16;   // RNE, finite inputs
    return (u16)r;
}
__device__ __forceinline__ float bf16_to_f32(u16 h) {
    return __uint_as_float(((unsigned)h) << 16);
}

// ================= unified bf16x3 MFMA GEMM =================
// C = A*B (+bias): A [M,K] k-contig hi/lo, B given TRANSPOSED [N,K] k-contig
// hi/lo. M = gridDim.y*128, N = gridDim.x*128, K mult of 32.
// EPI=false: writes split hi/lo C [M,N] row-major (+ optional fp32 bias [M,N]).
// EPI=true : logits[b,n] += sum_m w[m]*tanh(C[m,n]) (atomic).
template <bool LOGITS>
__global__ __launch_bounds__(256) void mm3(
    const u16* __restrict__ Ahp, const u16* __restrict__ Alp, long batchA, int ldA,
    const u16* __restrict__ Bhp, const u16* __restrict__ Blp, long batchB, int ldB,
    int N, int K,
    const float* __restrict__ bias,
    u16* __restrict__ Ch, u16* __restrict__ Cl, long batchC,
    const float* __restrict__ w, float* __restrict__ logits)
{
    __shared__ u16 Ah[128 * 32], Al[128 * 32], Bh[128 * 32], Bl[128 * 32];
    const int tid = threadIdx.x;
    const int b   = blockIdx.z;
    const int m0  = blockIdx.y * 128;
    const int n0  = blockIdx.x * 128;
    const u16* Ahb = Ahp + (long)b * batchA;
    const u16* Alb = Alp + (long)b * batchA;
    const u16* Bhb = Bhp + (long)b * batchB;
    const u16* Blb = Blp + (long)b * batchB;
    const int wave = tid >> 6, lane = tid & 63, quad = lane >> 4, l16 = lane & 15;
    const int wm = (wave >> 1) * 64, wn = (wave & 1) * 64;
    floatx4 acc[4][4] = {};

    for (int k0 = 0; k0 < K; k0 += 32) {
#pragma unroll
        for (int i = 0; i < 2; ++i) {
            int c = i * 256 + tid;
            int row = c >> 2, ko = (c & 3) * 8;
            long ga = (long)(m0 + row) * ldA + k0 + ko;
            long gb = (long)(n0 + row) * ldB + k0 + ko;
            *(short8*)&Ah[row * 32 + ko] = *(const short8*)&Ahb[ga];
            *(short8*)&Al[row * 32 + ko] = *(const short8*)&Alb[ga];
            *(short8*)&Bh[row * 32 + ko] = *(const short8*)&Bhb[gb];
            *(short8*)&Bl[row * 32 + ko] = *(const short8*)&Blb[gb];
        }
        __syncthreads();
        short8 ah[4], al[4], bh[4], bl[4];
#pragma unroll
        for (int t4 = 0; t4 < 4; ++t4) {
            int am = wm + t4 * 16 + l16;
            ah[t4] = *(const short8*)&Ah[am * 32 + quad * 8];
            al[t4] = *(const short8*)&Al[am * 32 + quad * 8];
            int bn = wn + t4 * 16 + l16;
            bh[t4] = *(const short8*)&Bh[bn * 32 + quad * 8];
            bl[t4] = *(const short8*)&Bl[bn * 32 + quad * 8];
        }
#pragma unroll
        for (int mt = 0; mt < 4; ++mt)
#pragma unroll
            for (int nt = 0; nt < 4; ++nt) {
                floatx4 a0 = acc[mt][nt];
                a0 = __builtin_amdgcn_mfma_f32_16x16x32_bf16(ah[mt], bh[nt], a0, 0, 0, 0);
                a0 = __builtin_amdgcn_mfma_f32_16x16x32_bf16(ah[mt], bl[nt], a0, 0, 0, 0);
                a0 = __builtin_amdgcn_mfma_f32_16x16x32_bf16(al[mt], bh[nt], a0, 0, 0, 0);
                acc[mt][nt] = a0;
            }
        __syncthreads();
    }

    if constexpr (!LOGITS) {
        u16* Chb = Ch + (long)b * batchC;
        u16* Clb = Cl + (long)b * batchC;
#pragma unroll
        for (int mt = 0; mt < 4; ++mt)
#pragma unroll
            for (int nt = 0; nt < 4; ++nt)
#pragma unroll
                for (int r = 0; r < 4; ++r) {
                    int row = m0 + wm + mt * 16 + quad * 4 + r;
                    int col = n0 + wn + nt * 16 + l16;
                    float x = acc[mt][nt][r];
                    if (bias) x += bias[(long)row * N + col];
                    u16 h = f32_to_bf16(x);
                    u16 l = f32_to_bf16(x - bf16_to_f32(h));
                    Chb[(long)row * N + col] = h;
                    Clb[(long)row * N + col] = l;
                }
    } else {
        float cs[4] = {};
#pragma unroll
        for (int nt = 0; nt < 4; ++nt)
#pragma unroll
            for (int mt = 0; mt < 4; ++mt)
#pragma unroll
                for (int r = 0; r < 4; ++r) {
                    int row = m0 + wm + mt * 16 + quad * 4 + r;
                    cs[nt] = fmaf(w[row], fast_tanh(acc[mt][nt][r]), cs[nt]);
                }
        float* red = (float*)Ah;   // 8 x 128 floats (4 KB), safe post-loop
        const int r8 = (wave >> 1) * 4 + quad;
#pragma unroll
        for (int nt = 0; nt < 4; ++nt)
            red[r8 * 128 + wn + nt * 16 + l16] = cs[nt];
        __syncthreads();
        if (tid < 128) {
            float s = 0.f;
#pragma unroll
            for (int r = 0; r < 8; ++r) s += red[r * 128 + tid];
            atomicAdd(logits + (long)b * N + n0 + tid, s);
        }
    }
}

// ---------------- conversions ----------------
// elementwise split; grid*1024 must equal element count
__global__ __launch_bounds__(256) void split_kernel(
    const float* __restrict__ X, u16* __restrict__ Xh, u16* __restrict__ Xl)
{
    long i0 = ((long)blockIdx.x * 256 + threadIdx.x) * 4;
    float4 v = *(const float4*)(X + i0);
    float xs[4] = {v.x, v.y, v.z, v.w};
    u16 h[4], l[4];
#pragma unroll
    for (int i = 0; i < 4; ++i) {
        h[i] = f32_to_bf16(xs[i]);
        l[i] = f32_to_bf16(xs[i] - bf16_to_f32(h[i]));
    }
    *(ushort4*)(Xh + i0) = *(ushort4*)h;
    *(ushort4*)(Xl + i0) = *(ushort4*)l;
}

// transpose + split: src [b,R,C] -> dst [b,C,R]; grid (R/64, C/64, batch)
__global__ __launch_bounds__(256) void tsplit_kernel(
    const float* __restrict__ src, u16* __restrict__ dh, u16* __restrict__ dl,
    int R, int C)
{
    __shared__ float tile[64][65];
    const int b = blockIdx.z;
    const int r0 = blockIdx.x * 64, c0 = blockIdx.y * 64;
    const float* S = src + (long)b * R * C;
    const int t = threadIdx.x;
    const int lr = t >> 2, lc0 = (t & 3) * 16;
#pragma unroll
    for (int i = 0; i < 4; ++i)
        *(float4*)&tile[lr][lc0 + i * 4] =
            *(const float4*)(S + (long)(r0 + lr) * C + c0 + lc0 + i * 4);
    __syncthreads();
    u16 hbuf[16], lbuf[16];
#pragma unroll
    for (int i = 0; i < 16; ++i) {
        float x = tile[lc0 + i][lr];
        u16 hi = f32_to_bf16(x);
        hbuf[i] = hi;
        lbuf[i] = f32_to_bf16(x - bf16_to_f32(hi));
    }
    long o = (long)b * R * C + (long)(c0 + lr) * R + r0 + lc0;
    *(short8*)(dh + o)     = *(short8*)&hbuf[0];
    *(short8*)(dh + o + 8) = *(short8*)&hbuf[8];
    *(short8*)(dl + o)     = *(short8*)&lbuf[0];
    *(short8*)(dl + o + 8) = *(short8*)&lbuf[8];
}

// ---------------- fp32 GEMM (fallback tier only) ----------------
template <bool LOGITS>
__global__ __launch_bounds__(256) void gemm_core(
    const float* __restrict__ A, const float* __restrict__ Bm, float* __restrict__ C,
    const float* __restrict__ bias,
    int M, int N, int K,
    int sAm, int sAk, long batchA,
    int sBk, int sBn, long batchB,
    long batchC,
    const float* __restrict__ w, float* __restrict__ logits)
{
    __shared__ float As[BK][LDT];
    __shared__ float Bs[BK][LDT];
    const int tid = threadIdx.x;
    const int b   = blockIdx.z;
    const int m0  = blockIdx.y * BM;
    const int n0  = blockIdx.x * BN;
    const float* Ab = A  + (long)b * batchA;
    const float* Bb = Bm + (long)b * batchB;
    const int tm = tid >> 4, tn = tid & 15;
    float acc[8][8] = {};

    for (int k0 = 0; k0 < K; k0 += BK) {
        if (sAk == 1) {
#pragma unroll
            for (int i = 0; i < 2; ++i) {
                int idx = tid + i * 256;
                int m = idx >> 2, kg = (idx & 3) * 4;
                float4 v = *(const float4*)(Ab + (long)(m0 + m) * sAm + k0 + kg);
                As[kg+0][m] = v.x; As[kg+1][m] = v.y; As[kg+2][m] = v.z; As[kg+3][m] = v.w;
            }
        } else {
#pragma unroll
            for (int i = 0; i < 2; ++i) {
                int idx = tid + i * 256;
                int k = idx >> 5, mg = (idx & 31) * 4;
                float4 v = *(const float4*)(Ab + (long)(k0 + k) * sAk + m0 + mg);
                *(float4*)&As[k][mg] = v;
            }
        }
        if (sBn == 1) {
#pragma unroll
            for (int i = 0; i < 2; ++i) {
                int idx = tid + i * 256;
                int k = idx >> 5, ng = (idx & 31) * 4;
                float4 v = *(const float4*)(Bb + (long)(k0 + k) * sBk + n0 + ng);
                *(float4*)&Bs[k][ng] = v;
            }
        } else {
#pragma unroll
            for (int i = 0; i < 2; ++i) {
                int idx = tid + i * 256;
                int n = idx >> 2, kg = (idx & 3) * 4;
                float4 v = *(const float4*)(Bb + (long)(n0 + n) * sBn + k0 + kg);
                Bs[kg+0][n] = v.x; Bs[kg+1][n] = v.y; Bs[kg+2][n] = v.z; Bs[kg+3][n] = v.w;
            }
        }
        __syncthreads();
#pragma unroll
        for (int kk = 0; kk < BK; ++kk) {
            float a[8], bv[8];
            *(float4*)&a[0]  = *(const float4*)&As[kk][tm * 4];
            *(float4*)&a[4]  = *(const float4*)&As[kk][64 + tm * 4];
            *(float4*)&bv[0] = *(const float4*)&Bs[kk][tn * 4];
            *(float4*)&bv[4] = *(const float4*)&Bs[kk][64 + tn * 4];
#pragma unroll
            for (int i = 0; i < 8; ++i)
#pragma unroll
                for (int j = 0; j < 8; ++j)
                    acc[i][j] = fmaf(a[i], bv[j], acc[i][j]);
        }
        __syncthreads();
    }

    if constexpr (!LOGITS) {
        float* Cb = C + (long)b * batchC;
#pragma unroll
        for (int i = 0; i < 8; ++i) {
            int row = m0 + (i >> 2) * 64 + tm * 4 + (i & 3);
            float* crow = Cb + (long)row * N + n0;
            float4 o0 = {acc[i][0], acc[i][1], acc[i][2], acc[i][3]};
            float4 o1 = {acc[i][4], acc[i][5], acc[i][6], acc[i][7]};
            if (bias) {
                const float* brow = bias + (long)row * N + n0;
                float4 b0 = *(const float4*)(brow + tn * 4);
                float4 b1 = *(const float4*)(brow + 64 + tn * 4);
                o0.x += b0.x; o0.y += b0.y; o0.z += b0.z; o0.w += b0.w;
                o1.x += b1.x; o1.y += b1.y; o1.z += b1.z; o1.w += b1.w;
            }
            *(float4*)(crow + tn * 4) = o0;
            *(float4*)(crow + 64 + tn * 4) = o1;
        }
    } else {
        float wv[8];
#pragma unroll
        for (int i = 0; i < 8; ++i) wv[i] = w[m0 + (i >> 2) * 64 + tm * 4 + (i & 3)];
        float cs[8];
#pragma unroll
        for (int j = 0; j < 8; ++j) {
            float s = 0.f;
#pragma unroll
            for (int i = 0; i < 8; ++i) s = fmaf(wv[i], fast_tanh(acc[i][j]), s);
            cs[j] = s;
        }
        __syncthreads();
        *(float4*)&As[tm][tn * 4]      = *(float4*)&cs[0];
        *(float4*)&As[tm][64 + tn * 4] = *(float4*)&cs[4];
        __syncthreads();
        if (tid < 128) {
            float s = 0.f;
#pragma unroll
            for (int r = 0; r < 16; ++r) s += As[r][tid];
            atomicAdd(logits + (long)b * N + n0 + tid, s);
        }
    }
}

// ---------------- small kernels ----------------
__global__ __launch_bounds__(256) void softmax_kernel(
    const float* __restrict__ lv, const float* __restrict__ lq, float* __restrict__ out)
{
    const int b = blockIdx.x;
    const int which = blockIdx.y;
    const float* x = (which == 0 ? lv : lq) + (long)b * 2048;
    float* o = out + (long)which * (Bn * 2048) + (long)b * 2048;
    const int tid = threadIdx.x;
    __shared__ float sm[4], ss[4];

    float m = -3.4e38f;
    for (int i = tid; i < 2048; i += 256) m = fmaxf(m, x[i]);
    for (int off = 32; off > 0; off >>= 1) m = fmaxf(m, __shfl_down(m, off));
    if ((tid & 63) == 0) sm[tid >> 6] = m;
    __syncthreads();
    m = fmaxf(fmaxf(sm[0], sm[1]), fmaxf(sm[2], sm[3]));

    float s = 0.f;
    for (int i = tid; i < 2048; i += 256) s += expf(x[i] - m);
    for (int off = 32; off > 0; off >>= 1) s += __shfl_down(s, off);
    if ((tid & 63) == 0) ss[tid >> 6] = s;
    __syncthreads();
    s = ss[0] + ss[1] + ss[2] + ss[3];
    float inv = 1.0f / s;
    for (int i = tid; i < 2048; i += 256) o[i] = expf(x[i] - m) * inv;
}

__global__ __launch_bounds__(256) void vout_kernel(
    const float* __restrict__ V, const float* __restrict__ av, float* __restrict__ vout)
{
    const int wave = threadIdx.x >> 6, lane = threadIdx.x & 63;
    const long idx = (long)blockIdx.x * 4 + wave;
    const int b = (int)(idx >> 10);
    const int h = (int)(idx & 1023);
    const float* vp = V + ((long)b * Hd + h) * NVn;
    const float* ap = av + (long)b * NVn;
    float s = 0.f;
    for (int i = lane; i < NVn; i += 64) s = fmaf(ap[i], vp[i], s);
    for (int off = 32; off > 0; off >>= 1) s += __shfl_down(s, off);
    if (lane == 0) vout[idx] = s;
}

__global__ __launch_bounds__(256) void qout_kernel(
    const float* __restrict__ Q, const float* __restrict__ aq, float* __restrict__ qout)
{
    const int h  = blockIdx.x * 256 + threadIdx.x;
    const int b  = blockIdx.z;
    const int q0 = blockIdx.y * 256;
    const float* qp = Q + (long)b * NQn * Hd;
    const float* ap = aq + (long)b * NQn + q0;
    float s = 0.f;
    for (int q = 0; q < 256; ++q) s = fmaf(ap[q], qp[(long)(q0 + q) * Hd + h], s);
    atomicAdd(qout + (long)b * Hd + h, s);
}

extern "C" void kernel_launch(void* const* d_in, const int* in_sizes, int n_in,
                              void* d_out, int out_size, void* d_ws, size_t ws_size,
                              hipStream_t stream) {
    const float* V    = (const float*)d_in[0];
    const float* Q    = (const float*)d_in[1];
    const float* W_b  = (const float*)d_in[2];
    const float* W_v  = (const float*)d_in[3];
    const float* W_q  = (const float*)d_in[4];
    const float* w_hv = (const float*)d_in[5];
    const float* w_hq = (const float*)d_in[6];
    float* out = (float*)d_out;
    dim3 blk(256);

    const long BIG  = (long)Bn * Hd * NVn;   // 33.55M (one big matrix, one half)
    const long GEL  = (long)Bn * Hd * Hd;    // 16.78M
    const long TEL  = (long)Bn * COn * Hd;   // 8.39M
    const long WQE  = (long)COn * Hd;        // 0.52M
    const long WBE  = (long)Hd * Hd;         // 1.05M

    // u16 layout
    u16* ws16 = (u16*)d_ws;
    u16* R1h  = ws16;            u16* R1l  = R1h + BIG;      // 134 MB shared region
    u16* Gh   = R1l + BIG;       u16* Gl   = Gh + GEL;       // 67 MB
    u16* Th   = Gl + GEL;        u16* Tl   = Th + TEL;       // 33.5 MB
    u16* Uh   = Gh;              u16* Ul   = Gh + TEL;       // U aliases dead G
    u16* Wqh  = Tl + TEL;        u16* Wql  = Wqh + WQE;
    u16* Wvh  = Wql + WQE;       u16* Wvl  = Wvh + WQE;
    u16* Wbh  = Wvl + WQE;       u16* Wbl  = Wbh + WBE;
    u16* WbTh = Wbl + WBE;       u16* WbTl = WbTh + WBE;
    float* lv = (float*)(WbTl + WBE);
    float* lq = lv + Bn * NVn;
    const size_t need = (size_t)((u16*)(lq + Bn * NQn) - ws16) * 2;

    float* vout_p = out + 2 * Bn * NVn;
    float* qout_p = vout_p + Bn * Hd;

    if (ws_size >= need) {
        hipMemsetAsync(lv, 0, (size_t)(Bn * NVn + Bn * NQn) * sizeof(float), stream);
        hipMemsetAsync(qout_p, 0, (size_t)Bn * Hd * sizeof(float), stream);

        // weight splits
        split_kernel<<<dim3((unsigned)(WQE / 1024)), blk, 0, stream>>>(W_q, Wqh, Wql);
        split_kernel<<<dim3((unsigned)(WQE / 1024)), blk, 0, stream>>>(W_v, Wvh, Wvl);
        split_kernel<<<dim3((unsigned)(WBE / 1024)), blk, 0, stream>>>(W_b, Wbh, Wbl);
        tsplit_kernel<<<dim3(Hd / 64, Hd / 64, 1), blk, 0, stream>>>(W_b, WbTh, WbTl, Hd, Hd);

        // ---- chain Q ----
        tsplit_kernel<<<dim3(NQn / 64, Hd / 64, Bn), blk, 0, stream>>>(Q, R1h, R1l, NQn, Hd);
        // G_Q = QT QT^T  [Hd,Hd]
        mm3<false><<<dim3(Hd / 128, Hd / 128, Bn), blk, 0, stream>>>(
            R1h, R1l, (long)Hd * NQn, NQn,  R1h, R1l, (long)Hd * NQn, NQn,
            Hd, NQn, nullptr, Gh, Gl, (long)Hd * Hd, nullptr, nullptr);
        // T = W_q @ G (G symmetric: B = G k-contig)
        mm3<false><<<dim3(Hd / 128, COn / 128, Bn), blk, 0, stream>>>(
            Wqh, Wql, 0L, Hd,  Gh, Gl, (long)Hd * Hd, Hd,
            Hd, Hd, nullptr, Th, Tl, (long)COn * Hd, nullptr, nullptr);
        // U = T @ W_b + W_v  (B = W_b^T pre-transposed)
        mm3<false><<<dim3(Hd / 128, COn / 128, Bn), blk, 0, stream>>>(
            Th, Tl, (long)COn * Hd, Hd,  WbTh, WbTl, 0L, Hd,
            Hd, Hd, W_v, Uh, Ul, (long)COn * Hd, nullptr, nullptr);
        // VT for logits B operand (QT dead)
        tsplit_kernel<<<dim3(Hd / 64, NVn / 64, Bn), blk, 0, stream>>>(V, R1h, R1l, Hd, NVn);
        // logits_v += w_hv . tanh(U @ V)
        mm3<true><<<dim3(NVn / 128, COn / 128, Bn), blk, 0, stream>>>(
            Uh, Ul, (long)COn * Hd, Hd,  R1h, R1l, (long)NVn * Hd, Hd,
            NVn, Hd, nullptr, nullptr, nullptr, 0L, w_hv, lv);

        // ---- chain V ----
        split_kernel<<<dim3((unsigned)(BIG / 1024)), blk, 0, stream>>>(V, R1h, R1l);
        // G_V = V V^T
        mm3<false><<<dim3(Hd / 128, Hd / 128, Bn), blk, 0, stream>>>(
            R1h, R1l, (long)Hd * NVn, NVn,  R1h, R1l, (long)Hd * NVn, NVn,
            Hd, NVn, nullptr, Gh, Gl, (long)Hd * Hd, nullptr, nullptr);
        // T = W_v @ G
        mm3<false><<<dim3(Hd / 128, COn / 128, Bn), blk, 0, stream>>>(
            Wvh, Wvl, 0L, Hd,  Gh, Gl, (long)Hd * Hd, Hd,
            Hd, Hd, nullptr, Th, Tl, (long)COn * Hd, nullptr, nullptr);
        // U = T @ W_b^T + W_q  (B = W_b row-major already [n,k])
        mm3<false><<<dim3(Hd / 128, COn / 128, Bn), blk, 0, stream>>>(
            Th, Tl, (long)COn * Hd, Hd,  Wbh, Wbl, 0L, Hd,
            Hd, Hd, W_q, Uh, Ul, (long)COn * Hd, nullptr, nullptr);
        // Q split (elementwise) for logits B operand (Vsplit dead)
        split_kernel<<<dim3((unsigned)(BIG / 1024)), blk, 0, stream>>>(Q, R1h, R1l);
        // logits_q += w_hq . tanh(U @ Q^T)
        mm3<true><<<dim3(NQn / 128, COn / 128, Bn), blk, 0, stream>>>(
            Uh, Ul, (long)COn * Hd, Hd,  R1h, R1l, (long)NQn * Hd, Hd,
            NQn, Hd, nullptr, nullptr, nullptr, 0L, w_hq, lq);

        softmax_kernel<<<dim3(Bn, 2), blk, 0, stream>>>(lv, lq, out);
        vout_kernel<<<dim3(Bn * Hd / 4), blk, 0, stream>>>(V, out, vout_p);
        qout_kernel<<<dim3(Hd / 256, NQn / 256, Bn), blk, 0, stream>>>(Q, out + Bn * NVn, qout_p);
        return;
    }

    // ---------------- fp32 fallback tier ----------------
    float* ws = (float*)d_ws;
    float* g  = ws;
    float* t  = g + GEL;
    float* u  = t + TEL;
    float* flv = u + TEL;
    float* flq = flv + Bn * NVn;

    hipMemsetAsync(flv, 0, (size_t)(Bn * NVn + Bn * NQn) * sizeof(float), stream);
    hipMemsetAsync(qout_p, 0, (size_t)Bn * Hd * sizeof(float), stream);

    gemm_core<false><<<dim3(Hd/BN, Hd/BM, Bn), blk, 0, stream>>>(Q, Q, g, nullptr,
        Hd, Hd, NQn, 1, Hd, (long)NQn*Hd, Hd, 1, (long)NQn*Hd, (long)Hd*Hd, nullptr, nullptr);
    gemm_core<false><<<dim3(Hd/BN, COn/BM, Bn), blk, 0, stream>>>(W_q, g, t, nullptr,
        COn, Hd, Hd, Hd, 1, 0L, Hd, 1, (long)Hd*Hd, (long)COn*Hd, nullptr, nullptr);
    gemm_core<false><<<dim3(Hd/BN, COn/BM, Bn), blk, 0, stream>>>(t, W_b, u, W_v,
        COn, Hd, Hd, Hd, 1, (long)COn*Hd, Hd, 1, 0L, (long)COn*Hd, nullptr, nullptr);
    gemm_core<true><<<dim3(NVn/BN, COn/BM, Bn), blk, 0, stream>>>(
        u, V, nullptr, nullptr, COn, NVn, Hd,
        Hd, 1, (long)COn*Hd, NVn, 1, (long)Hd*NVn, 0L, w_hv, flv);
    gemm_core<false><<<dim3(Hd/BN, Hd/BM, Bn), blk, 0, stream>>>(V, V, g, nullptr,
        Hd, Hd, NVn, NVn, 1, (long)Hd*NVn, 1, NVn, (long)Hd*NVn, (long)Hd*Hd, nullptr, nullptr);
    gemm_core<false><<<dim3(Hd/BN, COn/BM, Bn), blk, 0, stream>>>(W_v, g, t, nullptr,
        COn, Hd, Hd, Hd, 1, 0L, Hd, 1, (long)Hd*Hd, (long)COn*Hd, nullptr, nullptr);
    gemm_core<false><<<dim3(Hd/BN, COn/BM, Bn), blk, 0, stream>>>(t, W_b, u, W_q,
        COn, Hd, Hd, Hd, 1, (long)COn*Hd, 1, Hd, 0L, (long)COn*Hd, nullptr, nullptr);
    gemm_core<true><<<dim3(NQn/BN, COn/BM, Bn), blk, 0, stream>>>(
        u, Q, nullptr, nullptr, COn, NQn, Hd,
        Hd, 1, (long)COn*Hd, 1, Hd, (long)NQn*Hd, 0L, w_hq, flq);

    softmax_kernel<<<dim3(Bn, 2), blk, 0, stream>>>(flv, flq, out);
    vout_kernel<<<dim3(Bn * Hd / 4), blk, 0, stream>>>(V, out, vout_p);
    qout_kernel<<<dim3(Hd / 256, NQn / 256, Bn), blk, 0, stream>>>(Q, out + Bn * NVn, qout_p);
}